// Round 17
// baseline (69.022 us; speedup 1.0000x reference)
//
#include <hip/hip_runtime.h>
#include <math.h>

#define IOU_TH 0.5f
#define EPSF 1e-6f

__device__ __forceinline__ float sl1(float x) {
    float ax = fabsf(x);
    return ax < 1.f ? 0.5f * x * x : ax - 0.5f;
}

__device__ __forceinline__ int cell16(float v) {
    int c = (int)(v * 16.f);
    return min(max(c, 0), 15);
}

__device__ __forceinline__ int cellOf(float4 an) {   // 8x8 cell of anchor center
    int cx = (int)((an.x + an.z) * 0.5f * 8.f);
    int cy = (int)((an.y + an.w) * 0.5f * 8.f);
    cx = min(max(cx, 0), 7); cy = min(max(cy, 0), 7);
    return cy * 8 + cx;
}

// ---- K0 (fused prep): blocks [0,nCB): per-block 64-bin cell counts of anchors;
// ----                  blocks [nCB,nCB+B): per-sample gt grid + zero wsKey/histC/counter ----
__global__ __launch_bounds__(256) void kPrep(
    const float4* __restrict__ anchors, const float4* __restrict__ gt,
    int* __restrict__ gCnt, unsigned long long* __restrict__ gridMask,
    unsigned long long* __restrict__ wsKey, int* __restrict__ histC,
    int* __restrict__ counter, int A, int G, int nCB)
{
    __shared__ int cnt[64];
    __shared__ unsigned long long sCell[256];
    int t = threadIdx.x;
    if ((int)blockIdx.x < nCB) {
        if (t < 64) cnt[t] = 0;
        __syncthreads();
        int base = blockIdx.x * 1024;
        int end = min(base + 1024, A);
        for (int i = base + t; i < end; i += 256)
            atomicAdd(&cnt[cellOf(anchors[i])], 1);
        __syncthreads();
        if (t < 64) gCnt[blockIdx.x * 64 + t] = cnt[t];
    } else {
        int b = blockIdx.x - nCB;
        sCell[t] = 0ull;
        __syncthreads();
        if (t < G) {
            float4 g = gt[(size_t)b * G + t];
            int cx0 = cell16(g.x), cx1 = cell16(g.z);
            int cy0 = cell16(g.y), cy1 = cell16(g.w);
            unsigned long long bit = 1ull << t;
            for (int cy = cy0; cy <= cy1; ++cy)
                for (int cx = cx0; cx <= cx1; ++cx)
                    atomicOr(&sCell[cy * 16 + cx], bit);
        }
        __syncthreads();
        gridMask[(size_t)b * 256 + t] = sCell[t];
        if (t < 64) wsKey[(size_t)b * 64 + t] = 0ull;
        int4* hz = (int4*)(histC + (size_t)b * 4096);
        for (int i = t; i < 1024; i += 256) hz[i] = make_int4(0, 0, 0, 0);
        if (b == 0 && t == 0) *counter = 0;
    }
}

// ---- K0b: bin prefix + per-block offsets (1 block, 64 threads = 64 bins) ----
__global__ __launch_bounds__(64) void kScan(
    const int* __restrict__ gCnt, int* __restrict__ blockOff, int nCB)
{
    int t = threadIdx.x;          // bin
    int tot = 0;
    for (int blk = 0; blk < nCB; ++blk) tot += gCnt[blk * 64 + t];
    int inc = tot;
    for (int off = 1; off < 64; off <<= 1) {
        int o = __shfl_up(inc, off);
        if (t >= off) inc += o;
    }
    int run = inc - tot;          // exclusive prefix = global bin base
    for (int blk = 0; blk < nCB; ++blk) {
        blockOff[blk * 64 + t] = run;
        run += gCnt[blk * 64 + t];
    }
}

// ---- K0c: scatter anchor indices into cell-sorted perm ----
__global__ __launch_bounds__(256) void kScatter(
    const float4* __restrict__ anchors, const int* __restrict__ blockOff,
    int* __restrict__ perm, int A)
{
    __shared__ int loc[64];
    int t = threadIdx.x;
    if (t < 64) loc[t] = 0;
    __syncthreads();
    int base = blockIdx.x * 1024;
    int end = min(base + 1024, A);
    for (int i = base + t; i < end; i += 256) {
        int bin = cellOf(anchors[i]);
        int r = atomicAdd(&loc[bin], 1);
        perm[blockOff[blockIdx.x * 64 + bin] + r] = i;
    }
}

// ---- K1: screened single IoU pass over cell-sorted anchors (2/thread) ----
// Candidate gts via 16x16 bitmask; zero-IoU pairs skipped (cannot change either
// argmax: strict > vs init (0,1,0)). Forcing corrected in kFix.
__global__ __launch_bounds__(256) void kBig2(
    const float4* __restrict__ bbox, const float* __restrict__ conf,
    const float4* __restrict__ anchors, const float4* __restrict__ gt,
    const unsigned long long* __restrict__ gridMask, const int* __restrict__ perm,
    unsigned long long* __restrict__ wsKey,
    float* __restrict__ neg, int* __restrict__ histC, float4* __restrict__ part,
    int A, int G)
{
    __shared__ float4 sGt[64];
    __shared__ unsigned long long sGrid[256];
    __shared__ unsigned long long sKeyG[64];
    __shared__ int sHist[4096];
    __shared__ float red[4][4];
    int b = blockIdx.y, xb = blockIdx.x;
    for (int i = threadIdx.x; i < 4096; i += 256) sHist[i] = 0;
    if (threadIdx.x < 64) sKeyG[threadIdx.x] = 0ull;
    if (threadIdx.x < G) sGt[threadIdx.x] = gt[(size_t)b * G + threadIdx.x];
    sGrid[threadIdx.x] = gridMask[(size_t)b * 256 + threadIdx.x];

    int aSlot = xb * 512 + threadIdx.x;          // slot in cell-sorted order
    int ai[2];
    ai[0] = perm[aSlot];
    ai[1] = perm[aSlot + 256];
    float4 an[2], p4[2]; float cp[2], aa[2];
#pragma unroll
    for (int k = 0; k < 2; ++k) {
        an[k] = anchors[ai[k]];
        p4[k] = bbox[(size_t)b * A + ai[k]];
        cp[k] = conf[(size_t)b * A + ai[k]];
        aa[k] = (an[k].z - an[k].x) * (an[k].w - an[k].y);
    }
    __syncthreads();

    float Bi[2], Bd[2]; int Bx[2]; bool pos[2];
#pragma unroll
    for (int k = 0; k < 2; ++k) {
        int cx0 = cell16(an[k].x), cx1 = cell16(an[k].z);
        int cy0 = cell16(an[k].y), cy1 = cell16(an[k].w);
        unsigned long long m = 0ull;
        for (int cy = cy0; cy <= cy1; ++cy)
            for (int cx = cx0; cx <= cx1; ++cx)
                m |= sGrid[cy * 16 + cx];
        float bi = 0.f, bd = 1.f; int bx = 0;     // init == argmax-of-all-zeros (g=0)
        while (m) {
            int g = __ffsll((unsigned long long)m) - 1;
            m &= m - 1;
            float4 q = sGt[g];
            float gwa = (q.z - q.x) * (q.w - q.y);
            float wx = fmaxf(fminf(an[k].z, q.z) - fmaxf(an[k].x, q.x), 0.f);
            float wy = fmaxf(fminf(an[k].w, q.w) - fmaxf(an[k].y, q.y), 0.f);
            float inter = wx * wy;
            float den = aa[k] + gwa - inter + EPSF;
            if (inter * bd > bi * den) { bi = inter; bd = den; bx = g; }   // strict >, ascending g
            if (inter > 0.f) {
                float iouv = inter / den;
                unsigned long long key =
                    ((unsigned long long)__float_as_uint(iouv) << 32) |
                    (unsigned int)(~(unsigned int)ai[k]);
                atomicMax(&sKeyG[g], key);
            }
        }
        Bi[k] = bi; Bd[k] = bd; Bx[k] = bx;
        pos[k] = (bi / bd > IOU_TH);
    }

    float vloc = 0.f, vf = 0.f, vs = 0.f; int vn = 0;
    bool anyPos = __any(pos[0] | pos[1]);
#pragma unroll
    for (int k = 0; k < 2; ++k) {
        float box_loss = 0.f, a_iou = 0.f;
        if (anyPos) {                             // wave-uniform skip (~95% of waves)
            float4 m = sGt[Bx[k]];
            float pa = (p4[k].z - p4[k].x) * (p4[k].w - p4[k].y);
            float ta = (m.z - m.x) * (m.w - m.y);
            float wx = fmaxf(fminf(p4[k].z, m.z) - fmaxf(p4[k].x, m.x), 0.f);
            float wy = fmaxf(fminf(p4[k].w, m.w) - fmaxf(p4[k].y, m.y), 0.f);
            float inter = wx * wy;
            a_iou = inter / (pa + ta - inter + EPSF);
            float ex = fmaxf(fmaxf(p4[k].z, m.z) - fminf(p4[k].x, m.x), 0.f);
            float ey = fmaxf(fmaxf(p4[k].w, m.w) - fminf(p4[k].y, m.y), 0.f);
            float enc = ex * ey + EPSF;
            float uni = pa + ta - a_iou * pa * ta;
            float gl = 1.f - (a_iou - (enc - uni) / enc);
            float cl = sl1((p4[k].x + p4[k].z) * 0.5f - (m.x + m.z) * 0.5f)
                     + sl1((p4[k].y + p4[k].w) * 0.5f - (m.y + m.w) * 0.5f);
            float szl = sl1((p4[k].z - p4[k].x) - (m.z - m.x))
                      + sl1((p4[k].w - p4[k].y) - (m.w - m.y));
            box_loss = 0.5f * (cl + szl) + 0.5f * gl;
        }
        float tt = pos[k] ? a_iou : 0.f;
        float pcl = fminf(fmaxf(cp[k], 1e-7f), 1.f - 1e-7f);
        float bce;
        if (anyPos) bce = -(tt * logf(pcl) + (1.f - tt) * log1pf(-pcl));
        else        bce = -log1pf(-pcl);          // t == 0 exactly
        float pt = (tt > 0.f) ? cp[k] : (1.f - cp[k]);
        float om = 1.f - pt;
        float f = om * om * ((tt > 0.f) ? 0.25f : 0.75f) * bce;

        neg[(size_t)b * A + ai[k]] = pos[k] ? 0.f : f;
        if (!pos[k]) atomicAdd(&sHist[__float_as_uint(f) >> 19], 1);
        vloc += pos[k] ? box_loss : 0.f;
        vf   += pos[k] ? f : 0.f;
        vs   += pos[k] ? a_iou : 0.f;
        vn   += pos[k] ? 1 : 0;
    }

    int lane = threadIdx.x & 63, wv = threadIdx.x >> 6;
    for (int off = 32; off > 0; off >>= 1) {
        vloc += __shfl_down(vloc, off);
        vf   += __shfl_down(vf, off);
        vs   += __shfl_down(vs, off);
        vn   += __shfl_down(vn, off);
    }
    if (lane == 0) { red[wv][0] = vloc; red[wv][1] = vf; red[wv][2] = vs; red[wv][3] = (float)vn; }
    __syncthreads();    // sKeyG atomics + sHist adds + red[] all complete
    if (threadIdx.x == 0) {
        float sl = 0.f, sf = 0.f, ss = 0.f, sn = 0.f;
#pragma unroll
        for (int w = 0; w < 4; ++w) { sl += red[w][0]; sf += red[w][1]; ss += red[w][2]; sn += red[w][3]; }
        part[(size_t)b * (A / 512) + xb] = make_float4(sl, sf, ss, sn);
    }
    if (threadIdx.x < 64) {
        unsigned long long kk = sKeyG[threadIdx.x];
        if (kk) atomicMax(&wsKey[(size_t)b * 64 + threadIdx.x], kk);
    }
    int* hb = histC + (size_t)b * 4096;
    for (int i = threadIdx.x; i < 4096; i += 256) {
        int c = sHist[i];
        if (c) atomicAdd(&hb[i], c);
    }
}

// ---- K2: forced-positive correction (per sample: <=64 anchors) ----
// Sequential full-G chain with init (0,1,0) == kBig2's screened chain bit-exactly.
__global__ __launch_bounds__(64) void kFix(
    const float4* __restrict__ bbox, const float* __restrict__ conf,
    const float4* __restrict__ anchors, const float4* __restrict__ gt,
    const unsigned long long* __restrict__ wsKey,
    float* __restrict__ neg, int* __restrict__ histC, float4* __restrict__ corr,
    int A, int G)
{
    __shared__ float4 sGt[64];
    __shared__ int sWin[64];
    int b = blockIdx.x, t = threadIdx.x;
    if (t < G) {
        sGt[t] = gt[(size_t)b * G + t];
        unsigned long long kk = wsKey[(size_t)b * 64 + t];
        sWin[t] = (kk == 0ull) ? 0 : (int)~(unsigned int)(kk & 0xFFFFFFFFull);
    }
    __syncthreads();
    float cl = 0.f, cf = 0.f, cs = 0.f; int cn = 0;
    if (t < G) {
        int aw = sWin[t];
        bool dup = false;
        for (int g2 = 0; g2 < t; ++g2) dup |= (sWin[g2] == aw);
        if (!dup) {
            float4 an = anchors[aw];
            float aa = (an.z - an.x) * (an.w - an.y);
            float bi = 0.f, bd = 1.f; int bx = 0;
            for (int g = 0; g < G; ++g) {
                float4 q = sGt[g];
                float gwa = (q.z - q.x) * (q.w - q.y);
                float wx = fmaxf(fminf(an.z, q.z) - fmaxf(an.x, q.x), 0.f);
                float wy = fmaxf(fminf(an.w, q.w) - fmaxf(an.y, q.y), 0.f);
                float inter = wx * wy;
                float den = aa + gwa - inter + EPSF;
                if (inter * bd > bi * den) { bi = inter; bd = den; bx = g; }
            }
            if (!(bi / bd > IOU_TH)) {             // kBig2 treated it negative -> correct
                float4 p4 = bbox[(size_t)b * A + aw];
                float cp = conf[(size_t)b * A + aw];
                float4 m = sGt[bx];
                float pa = (p4.z - p4.x) * (p4.w - p4.y);
                float ta = (m.z - m.x) * (m.w - m.y);
                float wx = fmaxf(fminf(p4.z, m.z) - fmaxf(p4.x, m.x), 0.f);
                float wy = fmaxf(fminf(p4.w, m.w) - fmaxf(p4.y, m.y), 0.f);
                float inter = wx * wy;
                float a_iou = inter / (pa + ta - inter + EPSF);
                float ex = fmaxf(fmaxf(p4.z, m.z) - fminf(p4.x, m.x), 0.f);
                float ey = fmaxf(fmaxf(p4.w, m.w) - fminf(p4.y, m.y), 0.f);
                float enc = ex * ey + EPSF;
                float uni = pa + ta - a_iou * pa * ta;
                float gl = 1.f - (a_iou - (enc - uni) / enc);
                float cl2 = sl1((p4.x + p4.z) * 0.5f - (m.x + m.z) * 0.5f)
                          + sl1((p4.y + p4.w) * 0.5f - (m.y + m.w) * 0.5f);
                float szl = sl1((p4.z - p4.x) - (m.z - m.x)) + sl1((p4.w - p4.y) - (m.w - m.y));
                float box_loss = 0.5f * (cl2 + szl) + 0.5f * gl;
                float pcl = fminf(fmaxf(cp, 1e-7f), 1.f - 1e-7f);
                float bceP = -(a_iou * logf(pcl) + (1.f - a_iou) * log1pf(-pcl));
                float omP = 1.f - cp;
                float f_new = omP * omP * 0.25f * bceP;
                float bce0 = -log1pf(-pcl);
                float om0 = cp;
                float f_old = om0 * om0 * 0.75f * bce0;
                atomicAdd(&histC[(size_t)b * 4096 + (__float_as_uint(f_old) >> 19)], -1);
                neg[(size_t)b * A + aw] = 0.f;
                cl = box_loss; cf = f_new; cs = a_iou; cn = 1;
            }
        }
    }
    for (int off = 32; off > 0; off >>= 1) {
        cl += __shfl_down(cl, off);
        cf += __shfl_down(cf, off);
        cs += __shfl_down(cs, off);
        cn += __shfl_down(cn, off);
    }
    if (t == 0) corr[b] = make_float4(cl, cf, cs, (float)cn);
}

// ---- K3: top-k sum via prebuilt hist + wave-shuffle scans + ticketed final reduce ----
__global__ __launch_bounds__(1024) void kSelectFinal(
    const float* __restrict__ neg, const int* __restrict__ histC,
    const float4* __restrict__ part, const float4* __restrict__ corr,
    float* __restrict__ cand, float4* __restrict__ accTot,
    int* __restrict__ counter, float* __restrict__ out, int A, int nxb)
{
    __shared__ int cnt[1024];
    __shared__ float sm[1024];
    __shared__ int shI[16];
    __shared__ float shF[16];
    __shared__ float redF[16];
    __shared__ float sLoc, sFpos, sSiou; __shared__ int sNpos;
    __shared__ int sh_cb, sh_rem, sh_n, sh_done;
    __shared__ float sh_res, sh_sumHigh;

    int b = blockIdx.x;
    int t = threadIdx.x;
    int lane = t & 63, wv = t >> 6;

    if (t < 64) {   // sum per-block partials + correction
        float4 p = make_float4(0.f, 0.f, 0.f, 0.f);
        if (t < nxb) p = part[(size_t)b * nxb + t];
        float pl = p.x, pf = p.y, ps = p.z, pn = p.w;
        for (int off = 32; off > 0; off >>= 1) {
            pl += __shfl_down(pl, off);
            pf += __shfl_down(pf, off);
            ps += __shfl_down(ps, off);
            pn += __shfl_down(pn, off);
        }
        if (t == 0) {
            float4 c = corr[b];
            sLoc = pl + c.x; sFpos = pf + c.y; sSiou = ps + c.z;
            sNpos = (int)(pn + 0.5f) + (int)(c.w + 0.5f);
        }
    }
    __syncthreads();
    int npos = sNpos;
    int k = min(npos * 3, A - npos);
    float confSum;
    if (k <= 0) {
        confSum = sFpos;
    } else {
        int4 c4 = ((const int4*)(histC + (size_t)b * 4096))[t];
        int v0 = c4.x + c4.y + c4.z + c4.w;
        int ci = v0;
        for (int off = 1; off < 64; off <<= 1) {
            int oi = __shfl_down(ci, off);
            if (lane + off < 64) ci += oi;
        }
        if (lane == 0) shI[wv] = ci;
        __syncthreads();
        int addI = 0;
        for (int w = wv + 1; w < 16; ++w) addI += shI[w];
        int si = ci + addI;
        int above = si - v0;
        if (above < k && si >= k) {
            int carr[4] = {c4.x, c4.y, c4.z, c4.w};
            int cum = above;
            for (int j = 3; j >= 0; --j) {
                cum += carr[j];
                if (cum >= k) { sh_cb = 4 * t + j; sh_rem = k - (cum - carr[j]); break; }
            }
            sh_n = 0; sh_res = 0.f; sh_done = 0;
        }
        __syncthreads();
        int cb = sh_cb;
        float localSum = 0.f;
        const float4* nb4 = (const float4*)(neg + (size_t)b * A);
        float* cb_buf = cand + (size_t)b * A;
        for (int i = t; i < A / 4; i += 1024) {
            float4 v = nb4[i];
            float vv[4] = {v.x, v.y, v.z, v.w};
#pragma unroll
            for (int j = 0; j < 4; ++j) {
                int bin = (int)(__float_as_uint(vv[j]) >> 19);
                if (bin > cb) localSum += vv[j];
                else if (bin == cb) {
                    int idx = atomicAdd(&sh_n, 1);
                    cb_buf[idx] = vv[j];
                }
            }
        }
        for (int off = 32; off > 0; off >>= 1) localSum += __shfl_down(localSum, off);
        if (lane == 0) redF[wv] = localSum;
        __syncthreads();
        if (t == 0) {
            float tot = 0.f;
            for (int w = 0; w < 16; ++w) tot += redF[w];
            sh_sumHigh = tot;
        }
        __syncthreads();
        int n = sh_n;
        int rem = sh_rem;
        cnt[t] = 0; sm[t] = 0.f;
        __syncthreads();
        for (int i = t; i < n; i += 1024) {
            float v = cb_buf[i];
            int bin = (int)((__float_as_uint(v) >> 9) & 1023u);
            atomicAdd(&cnt[bin], 1);
            atomicAdd(&sm[bin], v);
        }
        __syncthreads();
        int v1 = cnt[t]; float f1 = sm[t];
        {
            int ci1 = v1; float cf1 = f1;
            for (int off = 1; off < 64; off <<= 1) {
                int oi = __shfl_down(ci1, off);
                float of = __shfl_down(cf1, off);
                if (lane + off < 64) { ci1 += oi; cf1 += of; }
            }
            if (lane == 0) { shI[wv] = ci1; shF[wv] = cf1; }
            __syncthreads();
            int aI = 0; float aF = 0.f;
            for (int w = wv + 1; w < 16; ++w) { aI += shI[w]; aF += shF[w]; }
            int s1 = ci1 + aI; float sf1 = cf1 + aF;
            int aboveC = s1 - v1; float aboveS = sf1 - f1;
            if (aboveC < rem && s1 >= rem) {
                int need = rem - aboveC;
                if (v1 == need) { sh_res += aboveS + f1; sh_done = 1; }
                else { sh_res += aboveS; sh_rem = need; sh_cb = t; }
            }
        }
        __syncthreads();
        if (!sh_done) {
            int cb2 = sh_cb;
            rem = sh_rem;
            if (t < 512) { cnt[t] = 0; sm[t] = 0.f; }
            __syncthreads();
            for (int i = t; i < n; i += 1024) {
                float v = cb_buf[i];
                unsigned int u = __float_as_uint(v);
                if ((int)((u >> 9) & 1023u) == cb2) {
                    int bin = (int)(u & 511u);
                    atomicAdd(&cnt[bin], 1);
                    atomicAdd(&sm[bin], v);
                }
            }
            __syncthreads();
            int v2 = (t < 512) ? cnt[t] : 0;
            float f2 = (t < 512) ? sm[t] : 0.f;
            int ci2 = v2; float cf2 = f2;
            for (int off = 1; off < 64; off <<= 1) {
                int oi = __shfl_down(ci2, off);
                float of = __shfl_down(cf2, off);
                if (lane + off < 64) { ci2 += oi; cf2 += of; }
            }
            if (lane == 0) { shI[wv] = ci2; shF[wv] = cf2; }
            __syncthreads();
            int aI = 0; float aF = 0.f;
            for (int w = wv + 1; w < 16; ++w) { aI += shI[w]; aF += shF[w]; }
            int s2 = ci2 + aI; float sf2 = cf2 + aF;
            int aboveC = s2 - v2; float aboveS = sf2 - f2;
            if (aboveC < rem && s2 >= rem) {
                int need = rem - aboveC;
                if (v2 == need) {
                    sh_res += aboveS + f2;
                } else {
                    unsigned int u = ((unsigned int)cb << 19) | ((unsigned int)cb2 << 9) | (unsigned int)t;
                    sh_res += aboveS + (float)need * __uint_as_float(u);
                }
            }
            __syncthreads();
        }
        confSum = sh_sumHigh + sh_res + sFpos;
    }

    if (t == 0) {
        accTot[b] = make_float4(sLoc, confSum, sSiou, (float)npos);
        __threadfence();
        int nB = (int)gridDim.x;
        if (atomicAdd(counter, 1) == nB - 1) {
            __threadfence();
            float loc = 0.f, cf2 = 0.f, si2 = 0.f, np = 0.f;
            for (int i = 0; i < nB; ++i) {
                float4 a4 = accTot[i];
                loc += a4.x; cf2 += a4.y; si2 += a4.z; np += a4.w;
            }
            float denom = fmaxf(1.f, np);
            float tl = loc / denom, tc = cf2 / denom;
            out[0] = tl + tc;
            out[1] = tc;
            out[2] = tl;
            out[3] = si2 / denom;
        }
    }
}

extern "C" void kernel_launch(void* const* d_in, const int* in_sizes, int n_in,
                              void* d_out, int out_size, void* d_ws, size_t ws_size,
                              hipStream_t stream)
{
    const float4* bbox    = (const float4*)d_in[0];
    const float*  conf    = (const float*)d_in[1];
    const float4* anchors = (const float4*)d_in[2];
    const float4* gt      = (const float4*)d_in[3];
    int A = in_sizes[2] / 4;
    int B = in_sizes[1] / A;
    int G = in_sizes[3] / (4 * B);
    float* out = (float*)d_out;
    int nxb = A / 512;
    int nCB = (A + 1023) / 1024;

    char* ws = (char*)d_ws;
    size_t off = 0;
    float* neg  = (float*)(ws + off); off += (size_t)B * A * sizeof(float);
    float* cand = (float*)(ws + off); off += (size_t)B * A * sizeof(float);
    unsigned long long* gridMask = (unsigned long long*)(ws + off); off += (size_t)B * 256 * 8;
    unsigned long long* wsKey = (unsigned long long*)(ws + off); off += (size_t)B * 64 * 8;
    int* histC = (int*)(ws + off); off += (size_t)B * 4096 * sizeof(int);
    int* counter = (int*)(ws + off); off += 64;
    float4* part = (float4*)(ws + off); off += (size_t)B * nxb * sizeof(float4);
    float4* corr = (float4*)(ws + off); off += (size_t)B * sizeof(float4);
    float4* accTot = (float4*)(ws + off); off += (size_t)B * sizeof(float4);
    int* gCnt = (int*)(ws + off); off += (size_t)nCB * 64 * sizeof(int);
    int* blockOff = (int*)(ws + off); off += (size_t)nCB * 64 * sizeof(int);
    int* perm = (int*)(ws + off); off += (size_t)A * sizeof(int);

    kPrep<<<dim3(nCB + B), 256, 0, stream>>>(
        anchors, gt, gCnt, gridMask, wsKey, histC, counter, A, G, nCB);
    kScan<<<dim3(1), 64, 0, stream>>>(gCnt, blockOff, nCB);
    kScatter<<<dim3(nCB), 256, 0, stream>>>(anchors, blockOff, perm, A);
    kBig2<<<dim3(nxb, B), 256, 0, stream>>>(
        bbox, conf, anchors, gt, gridMask, perm, wsKey, neg, histC, part, A, G);
    kFix<<<dim3(B), 64, 0, stream>>>(
        bbox, conf, anchors, gt, wsKey, neg, histC, corr, A, G);
    kSelectFinal<<<dim3(B), 1024, 0, stream>>>(
        neg, histC, part, corr, cand, accTot, counter, out, A, nxb);
}

// Round 18
// 49.559 us; speedup vs baseline: 1.3927x; 1.3927x over previous
//
#include <hip/hip_runtime.h>
#include <math.h>

#define IOU_TH 0.5f
#define EPSF 1e-6f

__device__ __forceinline__ float sl1(float x) {
    float ax = fabsf(x);
    return ax < 1.f ? 0.5f * x * x : ax - 0.5f;
}

__device__ __forceinline__ unsigned long long umax64(unsigned long long a, unsigned long long b) {
    return a > b ? a : b;
}

__device__ __forceinline__ int cell16(float v) {
    int c = (int)(v * 16.f);
    return min(max(c, 0), 15);
}

// ---- K0: per-sample 16x16 gt bitmask grid + zero wsKey/histC/counter ----
__global__ __launch_bounds__(256) void kGrid(
    const float4* __restrict__ gt, unsigned long long* __restrict__ gridMask,
    unsigned long long* __restrict__ wsKey, int* __restrict__ histC,
    int* __restrict__ counter, int G)
{
    __shared__ unsigned long long sCell[256];
    int b = blockIdx.x, t = threadIdx.x;
    sCell[t] = 0ull;
    __syncthreads();
    if (t < G) {
        float4 g = gt[(size_t)b * G + t];
        int cx0 = cell16(g.x), cx1 = cell16(g.z);
        int cy0 = cell16(g.y), cy1 = cell16(g.w);
        unsigned long long bit = 1ull << t;
        for (int cy = cy0; cy <= cy1; ++cy)
            for (int cx = cx0; cx <= cx1; ++cx)
                atomicOr(&sCell[cy * 16 + cx], bit);
    }
    __syncthreads();
    gridMask[(size_t)b * 256 + t] = sCell[t];
    if (t < 64) wsKey[(size_t)b * 64 + t] = 0ull;
    int4* hz = (int4*)(histC + (size_t)b * 4096);
    for (int i = t; i < 1024; i += 256) hz[i] = make_int4(0, 0, 0, 0);
    if (b == 0 && t == 0) *counter = 0;
}

// ---- K1: single screened IoU pass: per-anchor argmax + per-gt winners + losses + hist ----
// 2 anchors/thread, grid (A/512, B). Candidate gts via 16x16 bitmask; zero-IoU pairs skipped
// (provably cannot change either argmax: strict > vs init (0,1,0)).
__global__ __launch_bounds__(256) void kBig2(
    const float4* __restrict__ bbox, const float* __restrict__ conf,
    const float4* __restrict__ anchors, const float4* __restrict__ gt,
    const unsigned long long* __restrict__ gridMask,
    unsigned long long* __restrict__ wsKey,
    float* __restrict__ neg, int* __restrict__ histC, float4* __restrict__ part,
    int A, int G)
{
    __shared__ float4 sGt[64];
    __shared__ unsigned long long sGrid[256];
    __shared__ unsigned long long sKeyG[64];
    __shared__ int sHist[4096];
    __shared__ float red[4][4];
    int b = blockIdx.y, xb = blockIdx.x;
    for (int i = threadIdx.x; i < 4096; i += 256) sHist[i] = 0;
    if (threadIdx.x < 64) sKeyG[threadIdx.x] = 0ull;
    if (threadIdx.x < G) sGt[threadIdx.x] = gt[(size_t)b * G + threadIdx.x];
    sGrid[threadIdx.x] = gridMask[(size_t)b * 256 + threadIdx.x];

    int aBase = xb * 512 + threadIdx.x;          // A % 512 == 0
    float4 an[2], p4[2]; float cp[2], aa[2];
#pragma unroll
    for (int k = 0; k < 2; ++k) {
        int a = aBase + k * 256;
        an[k] = anchors[a];
        p4[k] = bbox[(size_t)b * A + a];
        cp[k] = conf[(size_t)b * A + a];
        aa[k] = (an[k].z - an[k].x) * (an[k].w - an[k].y);
    }
    __syncthreads();

    float Bi[2], Bd[2]; int Bx[2]; bool pos[2];
#pragma unroll
    for (int k = 0; k < 2; ++k) {
        // gather candidate mask from the cells this anchor overlaps
        int cx0 = cell16(an[k].x), cx1 = cell16(an[k].z);
        int cy0 = cell16(an[k].y), cy1 = cell16(an[k].w);
        unsigned long long m = 0ull;
        for (int cy = cy0; cy <= cy1; ++cy)
            for (int cx = cx0; cx <= cx1; ++cx)
                m |= sGrid[cy * 16 + cx];
        // screened sequential argmax chain: init == argmax-of-all-zeros (g=0)
        float bi = 0.f, bd = 1.f; int bx = 0;
        int aIdx = aBase + k * 256;
        while (m) {
            int g = __ffsll((unsigned long long)m) - 1;
            m &= m - 1;
            float4 q = sGt[g];
            float gwa = (q.z - q.x) * (q.w - q.y);
            float wx = fmaxf(fminf(an[k].z, q.z) - fmaxf(an[k].x, q.x), 0.f);
            float wy = fmaxf(fminf(an[k].w, q.w) - fmaxf(an[k].y, q.y), 0.f);
            float inter = wx * wy;
            float den = aa[k] + gwa - inter + EPSF;
            if (inter * bd > bi * den) { bi = inter; bd = den; bx = g; }   // strict >, ascending g
            if (inter > 0.f) {                     // per-gt winner candidate
                float iouv = inter / den;
                unsigned long long key =
                    ((unsigned long long)__float_as_uint(iouv) << 32) |
                    (unsigned int)(~(unsigned int)aIdx);
                atomicMax(&sKeyG[g], key);
            }
        }
        Bi[k] = bi; Bd[k] = bd; Bx[k] = bx;
        pos[k] = (bi / bd > IOU_TH);               // forcing corrected in kFix
    }

    float vloc = 0.f, vf = 0.f, vs = 0.f; int vn = 0;
    bool anyPos = __any(pos[0] | pos[1]);
#pragma unroll
    for (int k = 0; k < 2; ++k) {
        float box_loss = 0.f, a_iou = 0.f;
        if (anyPos) {                              // wave-uniform skip (~95% of waves)
            float4 m = sGt[Bx[k]];
            float pa = (p4[k].z - p4[k].x) * (p4[k].w - p4[k].y);
            float ta = (m.z - m.x) * (m.w - m.y);
            float wx = fmaxf(fminf(p4[k].z, m.z) - fmaxf(p4[k].x, m.x), 0.f);
            float wy = fmaxf(fminf(p4[k].w, m.w) - fmaxf(p4[k].y, m.y), 0.f);
            float inter = wx * wy;
            a_iou = inter / (pa + ta - inter + EPSF);
            float ex = fmaxf(fmaxf(p4[k].z, m.z) - fminf(p4[k].x, m.x), 0.f);
            float ey = fmaxf(fmaxf(p4[k].w, m.w) - fminf(p4[k].y, m.y), 0.f);
            float enc = ex * ey + EPSF;
            float uni = pa + ta - a_iou * pa * ta;
            float gl = 1.f - (a_iou - (enc - uni) / enc);
            float cl = sl1((p4[k].x + p4[k].z) * 0.5f - (m.x + m.z) * 0.5f)
                     + sl1((p4[k].y + p4[k].w) * 0.5f - (m.y + m.w) * 0.5f);
            float szl = sl1((p4[k].z - p4[k].x) - (m.z - m.x))
                      + sl1((p4[k].w - p4[k].y) - (m.w - m.y));
            box_loss = 0.5f * (cl + szl) + 0.5f * gl;
        }
        float t = pos[k] ? a_iou : 0.f;
        float pcl = fminf(fmaxf(cp[k], 1e-7f), 1.f - 1e-7f);
        float bce;
        if (anyPos) bce = -(t * logf(pcl) + (1.f - t) * log1pf(-pcl));
        else        bce = -log1pf(-pcl);           // t == 0 exactly
        float pt = (t > 0.f) ? cp[k] : (1.f - cp[k]);
        float om = 1.f - pt;
        float f = om * om * ((t > 0.f) ? 0.25f : 0.75f) * bce;

        neg[(size_t)b * A + aBase + k * 256] = pos[k] ? 0.f : f;
        if (!pos[k]) atomicAdd(&sHist[__float_as_uint(f) >> 19], 1);
        vloc += pos[k] ? box_loss : 0.f;
        vf   += pos[k] ? f : 0.f;
        vs   += pos[k] ? a_iou : 0.f;
        vn   += pos[k] ? 1 : 0;
    }

    int lane = threadIdx.x & 63, wv = threadIdx.x >> 6;
    for (int off = 32; off > 0; off >>= 1) {
        vloc += __shfl_down(vloc, off);
        vf   += __shfl_down(vf, off);
        vs   += __shfl_down(vs, off);
        vn   += __shfl_down(vn, off);
    }
    if (lane == 0) { red[wv][0] = vloc; red[wv][1] = vf; red[wv][2] = vs; red[wv][3] = (float)vn; }
    __syncthreads();    // sKeyG atomics + sHist adds + red[] all complete
    if (threadIdx.x == 0) {
        float sl = 0.f, sf = 0.f, ss = 0.f, sn = 0.f;
#pragma unroll
        for (int w = 0; w < 4; ++w) { sl += red[w][0]; sf += red[w][1]; ss += red[w][2]; sn += red[w][3]; }
        part[(size_t)b * (A / 512) + xb] = make_float4(sl, sf, ss, sn);
    }
    if (threadIdx.x < 64) {
        unsigned long long kk = sKeyG[threadIdx.x];
        if (kk) atomicMax(&wsKey[(size_t)b * 64 + threadIdx.x], kk);
    }
    int* hb = histC + (size_t)b * 4096;
    for (int i = threadIdx.x; i < 4096; i += 256) {
        int c = sHist[i];
        if (c) atomicAdd(&hb[i], c);
    }
}

// ---- K2: forced-positive correction (per sample: <=64 anchors) ----
// Sequential full-G chain with init (0,1,0) == kBig2's screened chain bit-exactly.
__global__ __launch_bounds__(64) void kFix(
    const float4* __restrict__ bbox, const float* __restrict__ conf,
    const float4* __restrict__ anchors, const float4* __restrict__ gt,
    const unsigned long long* __restrict__ wsKey,
    float* __restrict__ neg, int* __restrict__ histC, float4* __restrict__ corr,
    int A, int G)
{
    __shared__ float4 sGt[64];
    __shared__ int sWin[64];
    int b = blockIdx.x, t = threadIdx.x;
    if (t < G) {
        sGt[t] = gt[(size_t)b * G + t];
        unsigned long long kk = wsKey[(size_t)b * 64 + t];
        sWin[t] = (kk == 0ull) ? 0 : (int)~(unsigned int)(kk & 0xFFFFFFFFull);
    }
    __syncthreads();
    float cl = 0.f, cf = 0.f, cs = 0.f; int cn = 0;
    if (t < G) {
        int aw = sWin[t];
        bool dup = false;
        for (int g2 = 0; g2 < t; ++g2) dup |= (sWin[g2] == aw);
        if (!dup) {
            float4 an = anchors[aw];
            float aa = (an.z - an.x) * (an.w - an.y);
            float bi = 0.f, bd = 1.f; int bx = 0;
            for (int g = 0; g < G; ++g) {
                float4 q = sGt[g];
                float gwa = (q.z - q.x) * (q.w - q.y);
                float wx = fmaxf(fminf(an.z, q.z) - fmaxf(an.x, q.x), 0.f);
                float wy = fmaxf(fminf(an.w, q.w) - fmaxf(an.y, q.y), 0.f);
                float inter = wx * wy;
                float den = aa + gwa - inter + EPSF;
                if (inter * bd > bi * den) { bi = inter; bd = den; bx = g; }
            }
            if (!(bi / bd > IOU_TH)) {             // kBig2 treated it negative -> correct
                float4 p4 = bbox[(size_t)b * A + aw];
                float cp = conf[(size_t)b * A + aw];
                float4 m = sGt[bx];
                float pa = (p4.z - p4.x) * (p4.w - p4.y);
                float ta = (m.z - m.x) * (m.w - m.y);
                float wx = fmaxf(fminf(p4.z, m.z) - fmaxf(p4.x, m.x), 0.f);
                float wy = fmaxf(fminf(p4.w, m.w) - fmaxf(p4.y, m.y), 0.f);
                float inter = wx * wy;
                float a_iou = inter / (pa + ta - inter + EPSF);
                float ex = fmaxf(fmaxf(p4.z, m.z) - fminf(p4.x, m.x), 0.f);
                float ey = fmaxf(fmaxf(p4.w, m.w) - fminf(p4.y, m.y), 0.f);
                float enc = ex * ey + EPSF;
                float uni = pa + ta - a_iou * pa * ta;
                float gl = 1.f - (a_iou - (enc - uni) / enc);
                float cl2 = sl1((p4.x + p4.z) * 0.5f - (m.x + m.z) * 0.5f)
                          + sl1((p4.y + p4.w) * 0.5f - (m.y + m.w) * 0.5f);
                float szl = sl1((p4.z - p4.x) - (m.z - m.x)) + sl1((p4.w - p4.y) - (m.w - m.y));
                float box_loss = 0.5f * (cl2 + szl) + 0.5f * gl;
                float pcl = fminf(fmaxf(cp, 1e-7f), 1.f - 1e-7f);
                float bceP = -(a_iou * logf(pcl) + (1.f - a_iou) * log1pf(-pcl));
                float omP = 1.f - cp;
                float f_new = omP * omP * 0.25f * bceP;
                float bce0 = -log1pf(-pcl);
                float om0 = cp;
                float f_old = om0 * om0 * 0.75f * bce0;
                atomicAdd(&histC[(size_t)b * 4096 + (__float_as_uint(f_old) >> 19)], -1);
                neg[(size_t)b * A + aw] = 0.f;
                cl = box_loss; cf = f_new; cs = a_iou; cn = 1;
            }
        }
    }
    for (int off = 32; off > 0; off >>= 1) {
        cl += __shfl_down(cl, off);
        cf += __shfl_down(cf, off);
        cs += __shfl_down(cs, off);
        cn += __shfl_down(cn, off);
    }
    if (t == 0) corr[b] = make_float4(cl, cf, cs, (float)cn);
}

// ---- K3: top-k sum via prebuilt hist + wave-shuffle scans + ticketed final reduce ----
__global__ __launch_bounds__(1024) void kSelectFinal(
    const float* __restrict__ neg, const int* __restrict__ histC,
    const float4* __restrict__ part, const float4* __restrict__ corr,
    float* __restrict__ cand, float4* __restrict__ accTot,
    int* __restrict__ counter, float* __restrict__ out, int A, int nxb)
{
    __shared__ int cnt[1024];
    __shared__ float sm[1024];
    __shared__ int shI[16];
    __shared__ float shF[16];
    __shared__ float redF[16];
    __shared__ float sLoc, sFpos, sSiou; __shared__ int sNpos;
    __shared__ int sh_cb, sh_rem, sh_n, sh_done;
    __shared__ float sh_res, sh_sumHigh;

    int b = blockIdx.x;
    int t = threadIdx.x;
    int lane = t & 63, wv = t >> 6;

    if (t < 64) {   // sum per-block partials + correction
        float4 p = make_float4(0.f, 0.f, 0.f, 0.f);
        if (t < nxb) p = part[(size_t)b * nxb + t];
        float pl = p.x, pf = p.y, ps = p.z, pn = p.w;
        for (int off = 32; off > 0; off >>= 1) {
            pl += __shfl_down(pl, off);
            pf += __shfl_down(pf, off);
            ps += __shfl_down(ps, off);
            pn += __shfl_down(pn, off);
        }
        if (t == 0) {
            float4 c = corr[b];
            sLoc = pl + c.x; sFpos = pf + c.y; sSiou = ps + c.z;
            sNpos = (int)(pn + 0.5f) + (int)(c.w + 0.5f);
        }
    }
    __syncthreads();
    int npos = sNpos;
    int k = min(npos * 3, A - npos);
    float confSum;
    if (k <= 0) {
        confSum = sFpos;
    } else {
        int4 c4 = ((const int4*)(histC + (size_t)b * 4096))[t];
        int v0 = c4.x + c4.y + c4.z + c4.w;
        int ci = v0;
        for (int off = 1; off < 64; off <<= 1) {
            int oi = __shfl_down(ci, off);
            if (lane + off < 64) ci += oi;
        }
        if (lane == 0) shI[wv] = ci;
        __syncthreads();
        int addI = 0;
        for (int w = wv + 1; w < 16; ++w) addI += shI[w];
        int si = ci + addI;
        int above = si - v0;
        if (above < k && si >= k) {
            int carr[4] = {c4.x, c4.y, c4.z, c4.w};
            int cum = above;
            for (int j = 3; j >= 0; --j) {
                cum += carr[j];
                if (cum >= k) { sh_cb = 4 * t + j; sh_rem = k - (cum - carr[j]); break; }
            }
            sh_n = 0; sh_res = 0.f; sh_done = 0;
        }
        __syncthreads();
        int cb = sh_cb;
        float localSum = 0.f;
        const float4* nb4 = (const float4*)(neg + (size_t)b * A);
        float* cb_buf = cand + (size_t)b * A;
        for (int i = t; i < A / 4; i += 1024) {
            float4 v = nb4[i];
            float vv[4] = {v.x, v.y, v.z, v.w};
#pragma unroll
            for (int j = 0; j < 4; ++j) {
                int bin = (int)(__float_as_uint(vv[j]) >> 19);
                if (bin > cb) localSum += vv[j];
                else if (bin == cb) {
                    int idx = atomicAdd(&sh_n, 1);
                    cb_buf[idx] = vv[j];
                }
            }
        }
        for (int off = 32; off > 0; off >>= 1) localSum += __shfl_down(localSum, off);
        if (lane == 0) redF[wv] = localSum;
        __syncthreads();
        if (t == 0) {
            float tot = 0.f;
            for (int w = 0; w < 16; ++w) tot += redF[w];
            sh_sumHigh = tot;
        }
        __syncthreads();
        int n = sh_n;
        int rem = sh_rem;
        cnt[t] = 0; sm[t] = 0.f;
        __syncthreads();
        for (int i = t; i < n; i += 1024) {
            float v = cb_buf[i];
            int bin = (int)((__float_as_uint(v) >> 9) & 1023u);
            atomicAdd(&cnt[bin], 1);
            atomicAdd(&sm[bin], v);
        }
        __syncthreads();
        int v1 = cnt[t]; float f1 = sm[t];
        {
            int ci1 = v1; float cf1 = f1;
            for (int off = 1; off < 64; off <<= 1) {
                int oi = __shfl_down(ci1, off);
                float of = __shfl_down(cf1, off);
                if (lane + off < 64) { ci1 += oi; cf1 += of; }
            }
            if (lane == 0) { shI[wv] = ci1; shF[wv] = cf1; }
            __syncthreads();
            int aI = 0; float aF = 0.f;
            for (int w = wv + 1; w < 16; ++w) { aI += shI[w]; aF += shF[w]; }
            int s1 = ci1 + aI; float sf1 = cf1 + aF;
            int aboveC = s1 - v1; float aboveS = sf1 - f1;
            if (aboveC < rem && s1 >= rem) {
                int need = rem - aboveC;
                if (v1 == need) { sh_res += aboveS + f1; sh_done = 1; }
                else { sh_res += aboveS; sh_rem = need; sh_cb = t; }
            }
        }
        __syncthreads();
        if (!sh_done) {
            int cb2 = sh_cb;
            rem = sh_rem;
            if (t < 512) { cnt[t] = 0; sm[t] = 0.f; }
            __syncthreads();
            for (int i = t; i < n; i += 1024) {
                float v = cb_buf[i];
                unsigned int u = __float_as_uint(v);
                if ((int)((u >> 9) & 1023u) == cb2) {
                    int bin = (int)(u & 511u);
                    atomicAdd(&cnt[bin], 1);
                    atomicAdd(&sm[bin], v);
                }
            }
            __syncthreads();
            int v2 = (t < 512) ? cnt[t] : 0;
            float f2 = (t < 512) ? sm[t] : 0.f;
            int ci2 = v2; float cf2 = f2;
            for (int off = 1; off < 64; off <<= 1) {
                int oi = __shfl_down(ci2, off);
                float of = __shfl_down(cf2, off);
                if (lane + off < 64) { ci2 += oi; cf2 += of; }
            }
            if (lane == 0) { shI[wv] = ci2; shF[wv] = cf2; }
            __syncthreads();
            int aI = 0; float aF = 0.f;
            for (int w = wv + 1; w < 16; ++w) { aI += shI[w]; aF += shF[w]; }
            int s2 = ci2 + aI; float sf2 = cf2 + aF;
            int aboveC = s2 - v2; float aboveS = sf2 - f2;
            if (aboveC < rem && s2 >= rem) {
                int need = rem - aboveC;
                if (v2 == need) {
                    sh_res += aboveS + f2;
                } else {
                    unsigned int u = ((unsigned int)cb << 19) | ((unsigned int)cb2 << 9) | (unsigned int)t;
                    sh_res += aboveS + (float)need * __uint_as_float(u);
                }
            }
            __syncthreads();
        }
        confSum = sh_sumHigh + sh_res + sFpos;
    }

    if (t == 0) {
        accTot[b] = make_float4(sLoc, confSum, sSiou, (float)npos);
        __threadfence();
        int nB = (int)gridDim.x;
        if (atomicAdd(counter, 1) == nB - 1) {
            __threadfence();
            float loc = 0.f, cf2 = 0.f, si2 = 0.f, np = 0.f;
            for (int i = 0; i < nB; ++i) {
                float4 a4 = accTot[i];
                loc += a4.x; cf2 += a4.y; si2 += a4.z; np += a4.w;
            }
            float denom = fmaxf(1.f, np);
            float tl = loc / denom, tc = cf2 / denom;
            out[0] = tl + tc;
            out[1] = tc;
            out[2] = tl;
            out[3] = si2 / denom;
        }
    }
}

extern "C" void kernel_launch(void* const* d_in, const int* in_sizes, int n_in,
                              void* d_out, int out_size, void* d_ws, size_t ws_size,
                              hipStream_t stream)
{
    const float4* bbox    = (const float4*)d_in[0];
    const float*  conf    = (const float*)d_in[1];
    const float4* anchors = (const float4*)d_in[2];
    const float4* gt      = (const float4*)d_in[3];
    int A = in_sizes[2] / 4;
    int B = in_sizes[1] / A;
    int G = in_sizes[3] / (4 * B);
    float* out = (float*)d_out;
    int nxb = A / 512;

    char* ws = (char*)d_ws;
    size_t off = 0;
    float* neg  = (float*)(ws + off); off += (size_t)B * A * sizeof(float);
    float* cand = (float*)(ws + off); off += (size_t)B * A * sizeof(float);
    unsigned long long* gridMask = (unsigned long long*)(ws + off); off += (size_t)B * 256 * 8;
    unsigned long long* wsKey = (unsigned long long*)(ws + off); off += (size_t)B * 64 * 8;
    int* histC = (int*)(ws + off); off += (size_t)B * 4096 * sizeof(int);
    int* counter = (int*)(ws + off); off += 64;
    float4* part = (float4*)(ws + off); off += (size_t)B * nxb * sizeof(float4);
    float4* corr = (float4*)(ws + off); off += (size_t)B * sizeof(float4);
    float4* accTot = (float4*)(ws + off); off += (size_t)B * sizeof(float4);

    kGrid<<<dim3(B), 256, 0, stream>>>(gt, gridMask, wsKey, histC, counter, G);
    kBig2<<<dim3(nxb, B), 256, 0, stream>>>(
        bbox, conf, anchors, gt, gridMask, wsKey, neg, histC, part, A, G);
    kFix<<<dim3(B), 64, 0, stream>>>(
        bbox, conf, anchors, gt, wsKey, neg, histC, corr, A, G);
    kSelectFinal<<<dim3(B), 1024, 0, stream>>>(
        neg, histC, part, corr, cand, accTot, counter, out, A, nxb);
}